// Round 15
// baseline (238.719 us; speedup 1.0000x reference)
//
#include <hip/hip_runtime.h>
#include <cstdint>
#include <cstddef>

#define N_NODES 100000
#define N_EDGES 3200000
#define N_FEAT  512
#define HIDDEN  16
#define NBUCK   ((N_NODES + 127) / 128)   // 782 buckets of 128 rows
#define BCAP    4608                      // slots/bucket; mean 4092, +8 sigma
#define CHUNK   2048                      // edges per binscatter role-block
#define NGB     ((N_NODES + 255) / 256)   // 391 gemm role-blocks (256 rows)
#define NBS     ((N_EDGES + CHUNK - 1) / CHUNK)  // 1563 binscatter role-blocks
#define AGG_T   512

static_assert(4 * NGB >= NBS, "mod-5 interleave must cover all binscatter blocks");

// ---------------------------------------------------------------------------
// Prep: zero bucket cursors (replaces rocclr fillBuffer).
__global__ __launch_bounds__(256)
void k_prep(int* __restrict__ cursor) {
  const int i = blockIdx.x * 256 + threadIdx.x;
  if (i < NBUCK) cursor[i] = 0;
}

// ---------------------------------------------------------------------------
// MEGA4: mod-5 interleave — bid%5==0 -> register-GEMM role (no LDS),
// else -> stash-free binscatter role (3.1 KB LDS). Kernel LDS = 3.1 KB,
// occupancy wave-slot/VGPR-limited: launch_bounds(256,6) -> 24 waves/CU.
//
// GEMM role: xw[r][c] = sum_k x[r][k]*W1[k][c]. Lane = row (4 waves x 64
// distinct rows, full K=512). Per 16-float chunk the lane's 4 float4 loads
// are the 4 quarters of ONE 64B sector (back-to-back: 1 miss + 3 L1 hits,
// full sector consumption -> no over-fetch). 2-deep register pipeline:
// chunk ck+1 loads issue before ck's 256 FMAs; compiler places waitcnts.
// W1 rows are wave-uniform -> s_load. No LDS, no reduce, no barriers.
//
// binscatter role: phase 1 LDS histogram of row>>7; phase 2 ~780
// block-aggregated returned cursor atomics, hist := base in place; phase 3
// re-read inputs (L2-hot), off = atomicAdd(&hist[b],1) = base+rank, write
// packed {col | (row&127)<<20, val_bits}.
__global__ __launch_bounds__(256, 6)
void k_mega4(const float* __restrict__ x, const float* __restrict__ W1,
             float* __restrict__ xw, const int* __restrict__ rows,
             const int* __restrict__ cols, const float* __restrict__ vals,
             int* __restrict__ cursor, int2* __restrict__ binned) {
  __shared__ int hist[NBUCK];                   // binscatter only (3.13 KB)
  const int t = threadIdx.x;
  const int role = blockIdx.x % 5;

  if (role == 0) {
    // ---------------- register-GEMM role ----------------
    const int gid  = blockIdx.x / 5;
    const int rrow = gid * 256 + t;             // wave w covers rows [256g+64w, +64)
    const int grow = rrow < N_NODES ? rrow : N_NODES - 1;   // clamp loads
    const float* __restrict__ xr = x + (size_t)grow * N_FEAT;

    float acc[16];
#pragma unroll
    for (int c = 0; c < 16; ++c) acc[c] = 0.f;

    float4 c0 = *(const float4*)(xr + 0);
    float4 c1 = *(const float4*)(xr + 4);
    float4 c2 = *(const float4*)(xr + 8);
    float4 c3 = *(const float4*)(xr + 12);

#pragma unroll 1
    for (int ck = 0; ck < 32; ++ck) {
      const int kb = ck * 16;
      float4 n0 = c0, n1 = c1, n2 = c2, n3 = c3;
      if (ck + 1 < 32) {                        // issue next sector's 4 quarters
        const float* p = xr + kb + 16;
        n0 = *(const float4*)(p + 0);
        n1 = *(const float4*)(p + 4);
        n2 = *(const float4*)(p + 8);
        n3 = *(const float4*)(p + 12);
      }
      const float xe[16] = {c0.x, c0.y, c0.z, c0.w,  c1.x, c1.y, c1.z, c1.w,
                            c2.x, c2.y, c2.z, c2.w,  c3.x, c3.y, c3.z, c3.w};
#pragma unroll
      for (int j = 0; j < 16; ++j) {
        const float* wrow = W1 + (size_t)(kb + j) * 16;    // uniform -> s_load
#pragma unroll
        for (int c = 0; c < 16; ++c)
          acc[c] = fmaf(xe[j], wrow[c], acc[c]);
      }
      c0 = n0; c1 = n1; c2 = n2; c3 = n3;
    }

    if (rrow < N_NODES) {
      float4* o = (float4*)(xw + (size_t)rrow * 16);
      o[0] = make_float4(acc[0],  acc[1],  acc[2],  acc[3]);
      o[1] = make_float4(acc[4],  acc[5],  acc[6],  acc[7]);
      o[2] = make_float4(acc[8],  acc[9],  acc[10], acc[11]);
      o[3] = make_float4(acc[12], acc[13], acc[14], acc[15]);
    }
  } else {
    // ---------------- binscatter role (stash-free) ----------------
    const int bsid = (blockIdx.x / 5) * 4 + role - 1;
    if (bsid >= NBS) return;
    const int e0 = bsid * CHUNK;
    const int nv = (N_EDGES - e0 < CHUNK) ? (N_EDGES - e0) : CHUNK;

    for (int b = t; b < NBUCK; b += 256) hist[b] = 0;
    __syncthreads();

    for (int i = t; i < nv; i += 256)
      atomicAdd(&hist[rows[e0 + i] >> 7], 1);   // LDS atomic
    __syncthreads();

    for (int b = t; b < NBUCK; b += 256) {
      const int h = hist[b];
      hist[b] = (h > 0) ? atomicAdd(&cursor[b], h) : 0;  // global, aggregated
    }
    __syncthreads();

    for (int i = t; i < nv; i += 256) {
      const int e = e0 + i;
      const int r = rows[e];
      const int b = r >> 7;
      const int off = atomicAdd(&hist[b], 1);   // LDS atomic: base + rank
      if (off < BCAP)
        binned[(size_t)b * BCAP + off] =
            make_int2(cols[e] | ((r & 127) << 20), __float_as_int(vals[e]));
    }
  }
}

// ---------------------------------------------------------------------------
// SORTAGG (round-14 verbatim): per bucket (128 rows, 512 thr, 37.5 KB LDS):
// hist -> scan -> LDS-sorted stash -> binned2 writeback (drains under
// compute) -> layer-1 MLP from LDS broadcast descriptors -> hw1.
__global__ __launch_bounds__(AGG_T)
void k_sortagg(const int2* __restrict__ binned, const int* __restrict__ cursor,
               int2* __restrict__ binned2, int* __restrict__ row_beg,
               int* __restrict__ row_end, const float* __restrict__ xw,
               const float* __restrict__ b1, const float* __restrict__ W2,
               float* __restrict__ hw1) {
  __shared__ int2 stash[BCAP];                  // 36 KB
  __shared__ int hist[128];
  __shared__ int inc[128];
  __shared__ int cnt2[128];
  const int t = threadIdx.x;
  const int b = blockIdx.x;
  const int raw = cursor[b];
  const int cnt = raw < BCAP ? raw : BCAP;
  const int2* ep = binned + (size_t)b * BCAP;

  if (t < 128) { hist[t] = 0; cnt2[t] = 0; }
  __syncthreads();

  for (int i = t; i < cnt; i += AGG_T)
    atomicAdd(&hist[(ep[i].x >> 20) & 127], 1);         // LDS atomic
  __syncthreads();

  if (t < 128) inc[t] = hist[t];
  __syncthreads();
#pragma unroll
  for (int off = 1; off < 128; off <<= 1) {             // inclusive scan
    int add = (t >= off && t < 128) ? inc[t - off] : 0;
    __syncthreads();
    if (t < 128) inc[t] += add;
    __syncthreads();
  }

  if (t < 128) {
    const int r = b * 128 + t;
    if (r < N_NODES) {
      row_beg[r] = b * BCAP + inc[t] - hist[t];
      row_end[r] = b * BCAP + inc[t];
    }
  }

  for (int i = t; i < cnt; i += AGG_T) {                // placement
    const int2 e = ep[i];                               // L2-hot re-read
    const int row = (e.x >> 20) & 127;
    const int off = inc[row] - hist[row] + atomicAdd(&cnt2[row], 1);
    stash[off] = e;
  }
  __syncthreads();

  int2* eq = binned2 + (size_t)b * BCAP;                // writeback for fused2
  for (int i = t; i < cnt; i += AGG_T) eq[i] = stash[i];

  // ---- layer-1 MLP from LDS descriptors ----
  const int lane16 = t & 15;
  const int g = t >> 4;                                 // 0..31
  const float bb = b1[lane16];
  const float ww = W2[lane16];
#pragma unroll 1
  for (int rr = g; rr < 128; rr += 32) {
    const int r = b * 128 + rr;
    if (r >= N_NODES) continue;
    const int s = inc[rr] - hist[rr], e2 = inc[rr];
    float a0 = 0.f, a1 = 0.f, a2 = 0.f, a3 = 0.f;
    int i = s;
    for (; i + 3 < e2; i += 4) {                        // 4 independent chains
      int2 ea = stash[i],     eb = stash[i + 1];        // LDS broadcast
      int2 ec = stash[i + 2], ed = stash[i + 3];
      a0 = fmaf(__int_as_float(ea.y), xw[(size_t)(ea.x & 0xFFFFF) * 16 + lane16], a0);
      a1 = fmaf(__int_as_float(eb.y), xw[(size_t)(eb.x & 0xFFFFF) * 16 + lane16], a1);
      a2 = fmaf(__int_as_float(ec.y), xw[(size_t)(ec.x & 0xFFFFF) * 16 + lane16], a2);
      a3 = fmaf(__int_as_float(ed.y), xw[(size_t)(ed.x & 0xFFFFF) * 16 + lane16], a3);
    }
    for (; i < e2; ++i) {
      int2 ea = stash[i];
      a0 = fmaf(__int_as_float(ea.y), xw[(size_t)(ea.x & 0xFFFFF) * 16 + lane16], a0);
    }
    float h = fmaxf((a0 + a1) + (a2 + a3) + bb, 0.f);
    float p = h * ww;
#pragma unroll
    for (int m = 8; m >= 1; m >>= 1) p += __shfl_xor(p, m, 16);
    if (lane16 == 0) hw1[r] = p;
  }
}

// ---------------------------------------------------------------------------
// Fused layer-2 tail: gather-SPMM on scalars + bias + sigmoid -> out[r].
__global__ __launch_bounds__(256)
void k_fused2(const int2* __restrict__ binned2, const int* __restrict__ row_beg,
              const int* __restrict__ row_end, const float* __restrict__ hw1,
              const float* __restrict__ b2, float* __restrict__ out) {
  const int t = threadIdx.x;
  const int lane16 = t & 15;
  const int r = blockIdx.x * 16 + (t >> 4);
  if (r >= N_NODES) return;
  const int s = row_beg[r], e = row_end[r];
  float acc = 0.f;
  for (int i = s + lane16; i < e; i += 16) {
    int2 ev = binned2[i];
    acc = fmaf(__int_as_float(ev.y), hw1[ev.x & 0xFFFFF], acc);
  }
#pragma unroll
  for (int m = 8; m >= 1; m >>= 1) acc += __shfl_xor(acc, m, 16);
  if (lane16 == 0) out[r] = 1.f / (1.f + expf(-(acc + b2[0])));
}

// ---------------------------------------------------------------------------
extern "C" void kernel_launch(void* const* d_in, const int* in_sizes, int n_in,
                              void* d_out, int out_size, void* d_ws, size_t ws_size,
                              hipStream_t stream) {
  const float* x    = (const float*)d_in[0];
  const float* vals = (const float*)d_in[1];
  const float* W1   = (const float*)d_in[2];
  const float* b1   = (const float*)d_in[3];
  const float* W2   = (const float*)d_in[4];
  const float* b2   = (const float*)d_in[5];
  const int*   rows = (const int*)d_in[6];
  const int*   cols = (const int*)d_in[7];
  float* out = (float*)d_out;

  // workspace (~60 MB of the ~800 MB d_ws):
  // xw[N*16]f | binned[NBUCK*BCAP]int2 | binned2[NBUCK*BCAP]int2 |
  // cursor[NBUCK]i | row_beg[N]i | row_end[N]i | hw1[N]f
  char* w = (char*)d_ws;
  float* xw      = (float*)w;  w += (size_t)N_NODES * 16 * 4;
  int2*  binned  = (int2*)w;   w += (size_t)NBUCK * BCAP * 8;
  int2*  binned2 = (int2*)w;   w += (size_t)NBUCK * BCAP * 8;
  int*   cursor  = (int*)w;    w += (size_t)((NBUCK + 3) & ~3) * 4;
  int*   row_beg = (int*)w;    w += (size_t)N_NODES * 4;
  int*   row_end = (int*)w;    w += (size_t)N_NODES * 4;
  float* hw1     = (float*)w;

  k_prep    <<<(NBUCK + 255) / 256, 256,   0, stream>>>(cursor);
  k_mega4   <<<5 * NGB,             256,   0, stream>>>(x, W1, xw, rows, cols,
                                                        vals, cursor, binned);
  k_sortagg <<<NBUCK,               AGG_T, 0, stream>>>(binned, cursor, binned2,
                                                        row_beg, row_end, xw,
                                                        b1, W2, hw1);
  k_fused2  <<<(N_NODES + 15) / 16, 256,   0, stream>>>(binned2, row_beg, row_end,
                                                        hw1, b2, out);
}